// Round 17
// baseline (329.573 us; speedup 1.0000x reference)
//
#include <hip/hip_runtime.h>
#include <hip/hip_fp16.h>
#include <stdint.h>

#define DEVFN __device__ __forceinline__

// ---------------------------------------------------------------------------
// Compile-time exact Clebsch-Gordan tables (e3nn convention, real SH basis).
// ---------------------------------------------------------------------------
namespace cgc {

constexpr double fact(int n){ double r = 1.0; for(int i = 2; i <= n; ++i) r *= (double)i; return r; }

constexpr double csqrt(double x){
  if(x <= 0.0) return 0.0;
  double g = x < 1.0 ? 1.0 : x;
  for(int i = 0; i < 64; ++i) g = 0.5*(g + x/g);
  return g;
}

constexpr double su2_cg(int j1,int m1,int j2,int m2,int j3,int m3){
  if(m1 + m2 != m3) return 0.0;
  int vmin = -j1 + j2 + m3;
  if(-j1 + m1 > vmin) vmin = -j1 + m1;
  if(0 > vmin) vmin = 0;
  int vmax = j2 + j3 + m1;
  if(j3 - j1 + j2 < vmax) vmax = j3 - j1 + j2;
  if(j3 + m3 < vmax) vmax = j3 + m3;
  double C = (double)(2*j3 + 1)
    * (fact(j3 + j1 - j2)*fact(j3 - j1 + j2)*fact(j1 + j2 - j3)*fact(j3 + m3)*fact(j3 - m3))
    / (fact(j1 + j2 + j3 + 1)*fact(j1 - m1)*fact(j1 + m1)*fact(j2 - m2)*fact(j2 + m2));
  double S = 0.0;
  for(int v = vmin; v <= vmax; ++v){
    double t = (fact(j2 + j3 + m1 - v)*fact(j1 - m1 + v))
      / (fact(v)*fact(j3 - j1 + j2 - v)*fact(j3 + m3 - v)*fact(v + j1 - j2 - m3));
    S += (((v + j2 + m2) & 1) ? -t : t);
  }
  return csqrt(C)*S;
}

struct C2 { double re; double im; };
constexpr C2 cmul(C2 a, C2 b){ return C2{a.re*b.re - a.im*b.im, a.re*b.im + a.im*b.re}; }

struct QM { C2 q[5][5]; };

constexpr QM rtc(int l){
  QM Q{};
  for(int a = 0; a < 5; ++a) for(int b = 0; b < 5; ++b) Q.q[a][b] = C2{0.0,0.0};
  const double inv = 1.0/csqrt(2.0);
  for(int m = -l; m < 0; ++m){
    Q.q[l+m][l-m] = C2{inv, 0.0};
    Q.q[l+m][l+m] = C2{0.0, -inv};
  }
  Q.q[l][l] = C2{1.0, 0.0};
  for(int m = 1; m <= l; ++m){
    const double sgn = (m & 1) ? -1.0 : 1.0;
    Q.q[l+m][l+m] = C2{sgn*inv, 0.0};
    Q.q[l+m][l-m] = C2{0.0, sgn*inv};
  }
  const C2 ph = (l == 0) ? C2{1.0,0.0} : (l == 1) ? C2{0.0,-1.0} : C2{-1.0,0.0}; // (-i)^l
  for(int a = 0; a < 2*l+1; ++a) for(int b = 0; b < 2*l+1; ++b) Q.q[a][b] = cmul(ph, Q.q[a][b]);
  return Q;
}

struct CG3 { double a[5][5][5]; };

constexpr CG3 so3(int l1,int l2,int l3){
  const QM Q1 = rtc(l1), Q2 = rtc(l2), Q3 = rtc(l3);
  const int d1 = 2*l1+1, d2 = 2*l2+1, d3 = 2*l3+1;
  CG3 R{};
  for(int a = 0; a < 5; ++a) for(int b = 0; b < 5; ++b) for(int c = 0; c < 5; ++c) R.a[a][b][c] = 0.0;
  for(int i = 0; i < d1; ++i) for(int k = 0; k < d2; ++k){
    const int m1 = i - l1, m2 = k - l2;
    if(m1 + m2 < -l3 || m1 + m2 > l3) continue;
    const int n = m1 + m2 + l3;
    const double c = su2_cg(l1, m1, l2, m2, l3, m1 + m2);
    if(c == 0.0) continue;
    for(int j = 0; j < d1; ++j){
      const C2 q1 = Q1.q[i][j]; if(q1.re == 0.0 && q1.im == 0.0) continue;
      for(int l = 0; l < d2; ++l){
        const C2 q2 = Q2.q[k][l]; if(q2.re == 0.0 && q2.im == 0.0) continue;
        const C2 q12 = cmul(q1, q2);
        for(int m = 0; m < d3; ++m){
          const C2 q3 = Q3.q[n][m]; if(q3.re == 0.0 && q3.im == 0.0) continue;
          const C2 p = cmul(q12, C2{q3.re, -q3.im});
          R.a[j][l][m] += c*p.re;
        }
      }
    }
  }
  return R;
}

constexpr int NCOMB = 15;
constexpr int CDEG[NCOMB] = {0,0,0, 1,1,1,1,1,1, 2,2,2,2,2,2};
constexpr int CNI [NCOMB] = {0,1,2, 0,1,1,1,2,2, 0,1,1,2,2,2};
constexpr int CNO [NCOMB] = {0,1,2, 1,0,1,2,1,2, 2,1,2,0,1,2};
constexpr int BOFF[NCOMB] = {0,1,4, 9,12,13,16,21,24, 29,34,37,42,43,46};
constexpr int BTOT = 51;

struct Tables { float cg[NCOMB][5][5][5]; };
constexpr Tables build(){
  Tables t{};
  for(int ci = 0; ci < NCOMB; ++ci){
    const CG3 r = so3(CDEG[ci], CNI[ci], CNO[ci]);
    for(int i = 0; i < 5; ++i) for(int j = 0; j < 5; ++j) for(int k = 0; k < 5; ++k)
      t.cg[ci][i][j][k] = (float)r.a[i][j][k];
  }
  return t;
}

} // namespace cgc

__device__ constexpr cgc::Tables TAB = cgc::build();

// ---------------------------------------------------------------------------
// fp16 pack/unpack helpers
// ---------------------------------------------------------------------------
DEVFN uint32_t pack2(float a, float b){
  __half2 h = __floats2half2_rn(a, b);
  return *reinterpret_cast<uint32_t*>(&h);
}
DEVFN float2 unpack2(uint32_t u){
  __half2 h = *reinterpret_cast<__half2*>(&u);
  return __half22float2(h);
}

// ---------------------------------------------------------------------------
// Per-node CG contraction from the moment matrix M[9][5] (this lane's x-half).
// ---------------------------------------------------------------------------

template<int CI, int H>
DEVFN void contract_combo(const float (&M)[9][5], float (&bp)[cgc::BTOT]){
  constexpr int DEG = cgc::CDEG[CI];
  constexpr int NI  = cgc::CNI[CI];
  constexpr int NO  = cgc::CNO[CI];
  constexpr int DI = 2*DEG + 1, DJ = 2*NI + 1, DK = 2*NO + 1;
  constexpr int SHO = (DEG == 0) ? 0 : ((DEG == 1) ? 1 : 4);
  constexpr int XB  = (NI  == 0) ? 0 : ((NI  == 1) ? 1 : 4);
  constexpr int BO  = cgc::BOFF[CI];

#pragma unroll
  for(int k = 0; k < DK; ++k){
    float acc = 0.0f; bool any = false;
#pragma unroll
    for(int i = 0; i < DI; ++i){
#pragma unroll
      for(int j = 0; j < DJ; ++j){
        const int xj = XB + j;                 // compile-time post-unroll
        if(H == 0 && xj >= 4) continue;
        if(H == 1 && xj <  4) continue;
        const float cg = TAB.cg[CI][i][j][k];
        if(cg != 0.0f){ acc += cg * M[SHO + i][H ? (xj - 4) : xj]; any = true; }
      }
    }
    if(any) bp[BO + k] += acc;
  }
}

template<int H>
DEVFN void all_contract(const float (&M)[9][5], float (&bp)[cgc::BTOT]){
  contract_combo< 0,H>(M, bp);
  contract_combo< 1,H>(M, bp);
  contract_combo< 2,H>(M, bp);
  contract_combo< 3,H>(M, bp);
  contract_combo< 4,H>(M, bp);
  contract_combo< 5,H>(M, bp);
  contract_combo< 6,H>(M, bp);
  contract_combo< 7,H>(M, bp);
  contract_combo< 8,H>(M, bp);
  contract_combo< 9,H>(M, bp);
  contract_combo<10,H>(M, bp);
  contract_combo<11,H>(M, bp);
  contract_combo<12,H>(M, bp);
  contract_combo<13,H>(M, bp);
  contract_combo<14,H>(M, bp);
}

template<int CI>
DEVFN void combo_mix(const float (&B)[cgc::BTOT], float (&msg)[72],
                     const float* __restrict__ W, int c){
  constexpr int NO = cgc::CNO[CI];
  constexpr int DK = 2*NO + 1;
  constexpr int OO = (NO == 0) ? 0 : ((NO == 1) ? 8 : 32);
  constexpr int BO = cgc::BOFF[CI];
  const float* __restrict__ Wc = W + CI*64 + c*8;
#pragma unroll
  for(int o = 0; o < 8; ++o){
    const float w = Wc[o];
#pragma unroll
    for(int k = 0; k < DK; ++k) msg[OO + o*DK + k] += B[BO + k]*w;
  }
}

DEVFN void all_combo_mix(const float (&B)[cgc::BTOT], float (&msg)[72],
                         const float* __restrict__ W, int c){
  combo_mix< 0>(B, msg, W, c);
  combo_mix< 1>(B, msg, W, c);
  combo_mix< 2>(B, msg, W, c);
  combo_mix< 3>(B, msg, W, c);
  combo_mix< 4>(B, msg, W, c);
  combo_mix< 5>(B, msg, W, c);
  combo_mix< 6>(B, msg, W, c);
  combo_mix< 7>(B, msg, W, c);
  combo_mix< 8>(B, msg, W, c);
  combo_mix< 9>(B, msg, W, c);
  combo_mix<10>(B, msg, W, c);
  combo_mix<11>(B, msg, W, c);
  combo_mix<12>(B, msg, W, c);
  combo_mix<13>(B, msg, W, c);
  combo_mix<14>(B, msg, W, c);
}

// Shared node epilogue. OUTM: 0 = fp32 [N][72] rows; 1 = fp16 [N][8][12] slabs.
template<int OUTM>
DEVFN void node_epilogue(const float (&M)[9][5], const float* __restrict__ W,
                         int c, int sub, int g, void* __restrict__ outv){
  float bp[cgc::BTOT];
#pragma unroll
  for(int i = 0; i < cgc::BTOT; ++i) bp[i] = 0.0f;
  if(sub == 0) all_contract<0>(M, bp);
  else         all_contract<1>(M, bp);

#pragma unroll
  for(int i = 0; i < cgc::BTOT; ++i) bp[i] += __shfl_xor(bp[i], 8);

  float msg[72];
#pragma unroll
  for(int d = 0; d < 72; ++d) msg[d] = 0.0f;
  all_combo_mix(bp, msg, W, c);

#pragma unroll
  for(int d = 0; d < 72; ++d){
    msg[d] += __shfl_xor(msg[d], 1);
    msg[d] += __shfl_xor(msg[d], 2);
    msg[d] += __shfl_xor(msg[d], 4);
  }

  if constexpr(OUTM == 1){
    // fp16 packed slab write: lane c (sub==0) writes its channel's 12-half slab.
    if(sub == 0){
      float m0,m1,m2,m3,m4,m5,m6,m7,m8;
      switch(c){
        case 0: m0=msg[0]; m1=msg[ 8]; m2=msg[ 9]; m3=msg[10];
                m4=msg[32]; m5=msg[33]; m6=msg[34]; m7=msg[35]; m8=msg[36]; break;
        case 1: m0=msg[1]; m1=msg[11]; m2=msg[12]; m3=msg[13];
                m4=msg[37]; m5=msg[38]; m6=msg[39]; m7=msg[40]; m8=msg[41]; break;
        case 2: m0=msg[2]; m1=msg[14]; m2=msg[15]; m3=msg[16];
                m4=msg[42]; m5=msg[43]; m6=msg[44]; m7=msg[45]; m8=msg[46]; break;
        case 3: m0=msg[3]; m1=msg[17]; m2=msg[18]; m3=msg[19];
                m4=msg[47]; m5=msg[48]; m6=msg[49]; m7=msg[50]; m8=msg[51]; break;
        case 4: m0=msg[4]; m1=msg[20]; m2=msg[21]; m3=msg[22];
                m4=msg[52]; m5=msg[53]; m6=msg[54]; m7=msg[55]; m8=msg[56]; break;
        case 5: m0=msg[5]; m1=msg[23]; m2=msg[24]; m3=msg[25];
                m4=msg[57]; m5=msg[58]; m6=msg[59]; m7=msg[60]; m8=msg[61]; break;
        case 6: m0=msg[6]; m1=msg[26]; m2=msg[27]; m3=msg[28];
                m4=msg[62]; m5=msg[63]; m6=msg[64]; m7=msg[65]; m8=msg[66]; break;
        default:m0=msg[7]; m1=msg[29]; m2=msg[30]; m3=msg[31];
                m4=msg[67]; m5=msg[68]; m6=msg[69]; m7=msg[70]; m8=msg[71]; break;
      }
      uint2 u01, u23, u45;
      u01.x = pack2(m0, m1); u01.y = pack2(m2, m3);
      u23.x = pack2(m4, m5); u23.y = pack2(m6, m7);
      u45.x = pack2(m8, 0.f); u45.y = 0u;
      uint2* op = (uint2*)((uint32_t*)outv + (size_t)g*48 + c*6);
      op[0] = u01; op[1] = u23; op[2] = u45;
    }
  } else {
    if(sub == 0 && c == 0){
      float4* op = (float4*)((float*)outv + (size_t)g*72);
#pragma unroll
      for(int u = 0; u < 18; ++u){
        float4 v;
        v.x = msg[4*u + 0]; v.y = msg[4*u + 1];
        v.z = msg[4*u + 2]; v.w = msg[4*u + 3];
        op[u] = v;
      }
    }
  }
}

// ---------------------------------------------------------------------------
// CSR build — verbatim from round 3 (passed twelve times).
// ---------------------------------------------------------------------------

__global__ __launch_bounds__(256)
void hist_kernel(const int* __restrict__ ei, int* __restrict__ cnt, int E){
  const int e = blockIdx.x*256 + threadIdx.x;
  if(e < E) atomicAdd(&cnt[ei[E + e]], 1);
}

__global__ __launch_bounds__(256)
void chunk_scan_kernel(const int* __restrict__ cnt, int* __restrict__ off,
                       int* __restrict__ chunkSum, int N){
  __shared__ int buf[1024];
  const int tid = threadIdx.x;
  const int base = blockIdx.x*1024;
  for(int j = tid; j < 1024; j += 256) buf[j] = (base + j < N) ? cnt[base + j] : 0;
  __syncthreads();
  if(tid == 0){
    int run = 0;
    for(int j = 0; j < 1024; ++j){ const int v = buf[j]; buf[j] = run; run += v; }
    chunkSum[blockIdx.x] = run;
  }
  __syncthreads();
  for(int j = tid; j < 1024; j += 256) if(base + j < N) off[base + j] = buf[j];
}

__global__ __launch_bounds__(64)
void chunk_offsets_kernel(int* __restrict__ chunkSum, int* __restrict__ offN, int C){
  if(threadIdx.x == 0 && blockIdx.x == 0){
    int run = 0;
    for(int c = 0; c < C; ++c){ const int v = chunkSum[c]; chunkSum[c] = run; run += v; }
    offN[0] = run;
  }
}

__global__ __launch_bounds__(256)
void apply_offsets_kernel(int* __restrict__ off, int* __restrict__ cursor,
                          const int* __restrict__ chunkSum, int N){
  const int i = blockIdx.x*256 + threadIdx.x;
  if(i < N){
    const int o = off[i] + chunkSum[i >> 10];
    off[i] = o;
    cursor[i] = o;
  }
}

// tier-0 fill (R13-proven): srcs[p] + bucket-order-permuted fp16 sh row.
__global__ __launch_bounds__(256)
void fill_permute_h(const int* __restrict__ ei, int* __restrict__ cursor,
                    int* __restrict__ srcs, uint32_t* __restrict__ shpp,
                    const float* __restrict__ sh0, const float* __restrict__ sh1,
                    const float* __restrict__ sh2, int E){
  const int e = blockIdx.x*256 + threadIdx.x;
  if(e >= E) return;
  const int t = ei[E + e];
  const int p = atomicAdd(&cursor[t], 1);
  srcs[p] = ei[e];
  uint2 u01, u23, u45;
  u01.x = pack2(sh0[e],     sh1[3*e]);
  u01.y = pack2(sh1[3*e+1], sh1[3*e+2]);
  u23.x = pack2(sh2[5*e],   sh2[5*e+1]);
  u23.y = pack2(sh2[5*e+2], sh2[5*e+3]);
  u45.x = pack2(sh2[5*e+4], 0.f);
  u45.y = 0u;
  uint2* op = (uint2*)(shpp + (size_t)p*6);
  op[0] = u01; op[1] = u23; op[2] = u45;
}

// tier-2 fill (bare fallback, proven round 3)
__global__ __launch_bounds__(256)
void fill_kernel(const int* __restrict__ ei, int* __restrict__ cursor,
                 int* __restrict__ bucket, int E){
  const int e = blockIdx.x*256 + threadIdx.x;
  if(e >= E) return;
  const int t = ei[E + e];
  const int p = atomicAdd(&cursor[t], 1);
  bucket[p] = e;
}

// ---------------------------------------------------------------------------
// x packing to fp16 slabs (R13-proven): [n][72] f32 -> xph [n][8][12] halfs
// ---------------------------------------------------------------------------
__global__ __launch_bounds__(256)
void pack_x_h(const float* __restrict__ xin, uint32_t* __restrict__ xph, int N){
  const int idx = blockIdx.x*256 + threadIdx.x;
  if(idx >= N*8) return;
  const int n = idx >> 3, c = idx & 7;
  const float* row = xin + (size_t)n*72;
  uint2 u01, u23, u45;
  u01.x = pack2(row[c],        row[8+3*c]);
  u01.y = pack2(row[9+3*c],    row[10+3*c]);
  u23.x = pack2(row[32+5*c],   row[33+5*c]);
  u23.y = pack2(row[34+5*c],   row[35+5*c]);
  u45.x = pack2(row[36+5*c],   0.f);
  u45.y = 0u;
  uint2* op = (uint2*)(xph + (size_t)n*48 + c*6);
  op[0] = u01; op[1] = u23; op[2] = u45;
}

// ---------------------------------------------------------------------------
// Tier-0 gather (fp16 streams, PACKED pipeline): 16 lanes/node =
// 8 channels x 2 x-halves. Pipeline stages hold raw words (5 sh + 3 x = 8
// regs/stage instead of 14 unpacked floats); unpack happens at consume time
// inside acc_w (pairwise sh unpack, 2 live floats). Goal: VGPR < 85 for
// 6 waves/SIMD without launch-bounds forcing (R15 lesson: spills).
// ---------------------------------------------------------------------------

DEVFN void load_w(uint32_t (&sw)[5], uint32_t (&xw)[3],
                  int p, int c, int sub,
                  const int* __restrict__ srcs,
                  const uint32_t* __restrict__ shpp,
                  const uint32_t* __restrict__ xph){
  const uint2* sp = (const uint2*)(shpp + (size_t)p*6);
  const uint2 a = sp[0], b = sp[1];
  sw[0] = a.x; sw[1] = a.y; sw[2] = b.x; sw[3] = b.y;
  sw[4] = shpp[(size_t)p*6 + 4];
  const int src = srcs[p];
  const uint32_t* base = xph + (size_t)src*48 + c*6;
  const uint2 xv = *(const uint2*)(base + sub*2);    // words 0-1 or 2-3
  xw[0] = xv.x; xw[1] = xv.y; xw[2] = base[4];
}

DEVFN void acc_w(const uint32_t (&sw)[5], const uint32_t (&xw)[3],
                 int sub, float (&M)[9][5]){
  float xs[5];
  float2 f;
  f = unpack2(xw[0]); xs[0] = f.x; xs[1] = f.y;
  f = unpack2(xw[1]); xs[2] = f.x; xs[3] = f.y;
  f = unpack2(xw[2]); xs[4] = sub ? f.x : 0.0f;
#pragma unroll
  for(int w = 0; w < 5; ++w){
    const float2 s = unpack2(sw[w]);
    const int i0 = 2*w, i1 = 2*w + 1;
#pragma unroll
    for(int j = 0; j < 5; ++j) M[i0][j] += s.x*xs[j];
    if(i1 < 9){
#pragma unroll
      for(int j = 0; j < 5; ++j) M[i1][j] += s.y*xs[j];
    }
  }
}

template<int OUTM>
__global__ __launch_bounds__(256)
void gather_h(const uint32_t* __restrict__ xph,
              const uint32_t* __restrict__ shpp,
              const int*   __restrict__ srcs,
              const int*   __restrict__ off,
              const float* __restrict__ W,
              void* __restrict__ out,
              int N){
  const int t   = blockIdx.x*256 + threadIdx.x;
  const int g   = t >> 4;
  const int c   = t & 7;
  const int sub = (t >> 3) & 1;
  if(g >= N) return;

  const int pStart = off[g];
  const int pEnd   = off[g + 1];

  float M[9][5];
#pragma unroll
  for(int a = 0; a < 9; ++a)
#pragma unroll
    for(int b = 0; b < 5; ++b) M[a][b] = 0.0f;

  if(pStart < pEnd){
    uint32_t swA[5], xwA[3], swB[5], xwB[3], swC[5], xwC[3];
    int p = pStart;
    load_w(swA, xwA, p, c, sub, srcs, shpp, xph);
    { const int pn = (p + 1 < pEnd) ? p + 1 : p;
      load_w(swB, xwB, pn, c, sub, srcs, shpp, xph); }
    while(true){
      { const int pn = (p + 2 < pEnd) ? p + 2 : p;
        load_w(swC, xwC, pn, c, sub, srcs, shpp, xph); }
      acc_w(swA, xwA, sub, M);
      ++p; if(p >= pEnd) break;
      { const int pn = (p + 2 < pEnd) ? p + 2 : p;
        load_w(swA, xwA, pn, c, sub, srcs, shpp, xph); }
      acc_w(swB, xwB, sub, M);
      ++p; if(p >= pEnd) break;
      { const int pn = (p + 2 < pEnd) ? p + 2 : p;
        load_w(swB, xwB, pn, c, sub, srcs, shpp, xph); }
      acc_w(swC, xwC, sub, M);
      ++p; if(p >= pEnd) break;
    }
  }

  node_epilogue<OUTM>(M, W, c, sub, g, out);
}

// ---------------------------------------------------------------------------
// Tier-2 fallback gather (bare fp32, proven structure).
// ---------------------------------------------------------------------------

DEVFN void outer_acc(const float (&sh)[9], const float (&xs)[5], float (&M)[9][5]){
#pragma unroll
  for(int i = 0; i < 9; ++i)
#pragma unroll
    for(int j = 0; j < 5; ++j)
      M[i][j] += sh[i]*xs[j];
}

DEVFN void load_edge_f(float (&sh)[9], float (&xs)[5],
                       int eid, int src, int c, int sub,
                       const float* __restrict__ x,
                       const float* __restrict__ sh0, const float* __restrict__ sh1,
                       const float* __restrict__ sh2){
  sh[0] = sh0[eid];
  sh[1] = sh1[3*eid+0]; sh[2] = sh1[3*eid+1]; sh[3] = sh1[3*eid+2];
  sh[4] = sh2[5*eid+0]; sh[5] = sh2[5*eid+1]; sh[6] = sh2[5*eid+2];
  sh[7] = sh2[5*eid+3]; sh[8] = sh2[5*eid+4];
  const float* xrow = x + (size_t)src*72;
  if(sub == 0){
    xs[0] = xrow[c];
    xs[1] = xrow[8+3*c]; xs[2] = xrow[9+3*c]; xs[3] = xrow[10+3*c];
    xs[4] = 0.0f;
  } else {
#pragma unroll
    for(int k = 0; k < 5; ++k) xs[k] = xrow[32 + 5*c + k];
  }
}

__global__ __launch_bounds__(256)
void gather_f(const float* __restrict__ x,
              const int*   __restrict__ ei,
              const float* __restrict__ sh0,
              const float* __restrict__ sh1,
              const float* __restrict__ sh2,
              const int*   __restrict__ off,
              const int*   __restrict__ bucket,
              const float* __restrict__ W,
              float* __restrict__ out,
              int N){
  const int t   = blockIdx.x*256 + threadIdx.x;
  const int g   = t >> 4;
  const int c   = t & 7;
  const int sub = (t >> 3) & 1;
  if(g >= N) return;

  const int pStart = off[g];
  const int pEnd   = off[g + 1];

  float M[9][5];
#pragma unroll
  for(int a = 0; a < 9; ++a)
#pragma unroll
    for(int b = 0; b < 5; ++b) M[a][b] = 0.0f;

  if(pStart < pEnd){
    float shA[9], xsA[5], shB[9], xsB[5], shC[9], xsC[5];
    int p = pStart;
    { const int eid = bucket[p]; const int src = ei[eid];
      load_edge_f(shA, xsA, eid, src, c, sub, x, sh0, sh1, sh2); }
    { const int pn = (p + 1 < pEnd) ? p + 1 : p;
      const int eid = bucket[pn]; const int src = ei[eid];
      load_edge_f(shB, xsB, eid, src, c, sub, x, sh0, sh1, sh2); }
    while(true){
      { const int pn = (p + 2 < pEnd) ? p + 2 : p;
        const int eid = bucket[pn]; const int src = ei[eid];
        load_edge_f(shC, xsC, eid, src, c, sub, x, sh0, sh1, sh2); }
      outer_acc(shA, xsA, M);
      ++p; if(p >= pEnd) break;
      { const int pn = (p + 2 < pEnd) ? p + 2 : p;
        const int eid = bucket[pn]; const int src = ei[eid];
        load_edge_f(shA, xsA, eid, src, c, sub, x, sh0, sh1, sh2); }
      outer_acc(shB, xsB, M);
      ++p; if(p >= pEnd) break;
      { const int pn = (p + 2 < pEnd) ? p + 2 : p;
        const int eid = bucket[pn]; const int src = ei[eid];
        load_edge_f(shB, xsB, eid, src, c, sub, x, sh0, sh1, sh2); }
      outer_acc(shC, xsC, M);
      ++p; if(p >= pEnd) break;
    }
  }

  node_epilogue<0>(M, W, c, sub, g, (void*)out);
}

// ---------------------------------------------------------------------------

extern "C" void kernel_launch(void* const* d_in, const int* in_sizes, int n_in,
                              void* d_out, int out_size, void* d_ws, size_t ws_size,
                              hipStream_t stream){
  const float* node = (const float*)d_in[0];
  const int*   ei   = (const int*)  d_in[1];
  const float* sh0  = (const float*)d_in[2];
  const float* sh1  = (const float*)d_in[3];
  const float* sh2  = (const float*)d_in[4];
  const float* wts  = (const float*)d_in[5];
  float* out = (float*)d_out;

  const int E = in_sizes[1]/2;
  const int N = in_sizes[0]/72;
  const int C = (N + 1023)/1024;

  // ---- workspace tiers (4-byte units) ----
  size_t baseI = (size_t)3*N + 65;
  baseI = (baseI + 3) & ~(size_t)3;
  const size_t availI = ws_size/4;
  // tier 0: srcs[E] + shpp[6E words] + xph1[48N] + xph2[48N]
  const size_t t0Need = baseI + (size_t)E + (size_t)6*E + (size_t)48*N + (size_t)48*N;
  const int tier = (availI >= t0Need) ? 0 : 2;

  int* ws_i = (int*)d_ws;
  int* cnt      = ws_i;                       // [N]
  int* off      = ws_i + N;                   // [N+1]
  int* cursor   = ws_i + 2*N + 1;             // [N]
  int* chunkSum = ws_i + 3*N + 1;             // [C] (<=64)
  size_t cur = baseI;

  int*      srcs = nullptr;
  uint32_t* shpp = nullptr;
  uint32_t* xph1 = nullptr;
  uint32_t* xph2 = nullptr;
  int*      bucket = nullptr;
  float*    inter  = nullptr;

  if(tier == 0){
    srcs = (int*)(ws_i + cur);      cur += (size_t)E;
    shpp = (uint32_t*)(ws_i + cur); cur += (size_t)6*E;
    xph1 = (uint32_t*)(ws_i + cur); cur += (size_t)48*N;
    xph2 = (uint32_t*)(ws_i + cur); cur += (size_t)48*N;
  } else {
    bucket = (int*)(ws_i + cur);   cur += (size_t)E;
    inter  = (float*)(ws_i + cur); cur += (size_t)72*N;
  }

  const int eBlocks = (E + 255)/256;
  const int nBlocks = (N + 255)/256;
  const int gBlocks = ((size_t)16*N + 255)/256;   // 16 lanes per node

  // CSR build (targets identical for both layers)
  hipMemsetAsync(cnt, 0, (size_t)N*sizeof(int), stream);
  hist_kernel<<<eBlocks, 256, 0, stream>>>(ei, cnt, E);
  chunk_scan_kernel<<<C, 256, 0, stream>>>(cnt, off, chunkSum, N);
  chunk_offsets_kernel<<<1, 64, 0, stream>>>(chunkSum, off + N, C);
  apply_offsets_kernel<<<nBlocks, 256, 0, stream>>>(off, cursor, chunkSum, N);

  const float* w2 = wts + cgc::NCOMB*64;

  if(tier == 0){
    fill_permute_h<<<eBlocks, 256, 0, stream>>>(ei, cursor, srcs, shpp,
                                                sh0, sh1, sh2, E);
    pack_x_h<<<((size_t)8*N + 255)/256, 256, 0, stream>>>(node, xph1, N);
    // layer 1: xph1 -> xph2 (fp16 slabs)
    gather_h<1><<<gBlocks, 256, 0, stream>>>(xph1, shpp, srcs, off, wts, (void*)xph2, N);
    // layer 2: xph2 -> out (fp32)
    gather_h<0><<<gBlocks, 256, 0, stream>>>(xph2, shpp, srcs, off, w2, (void*)out, N);
  } else {
    fill_kernel<<<eBlocks, 256, 0, stream>>>(ei, cursor, bucket, E);
    gather_f<<<gBlocks, 256, 0, stream>>>(node,  ei, sh0, sh1, sh2,
                                          off, bucket, wts, inter, N);
    gather_f<<<gBlocks, 256, 0, stream>>>(inter, ei, sh0, sh1, sh2,
                                          off, bucket, w2, out, N);
  }
}

// Round 18
// 315.747 us; speedup vs baseline: 1.0438x; 1.0438x over previous
//
#include <hip/hip_runtime.h>
#include <hip/hip_fp16.h>
#include <stdint.h>

#define DEVFN __device__ __forceinline__

// ---------------------------------------------------------------------------
// Compile-time exact Clebsch-Gordan tables (e3nn convention, real SH basis).
// ---------------------------------------------------------------------------
namespace cgc {

constexpr double fact(int n){ double r = 1.0; for(int i = 2; i <= n; ++i) r *= (double)i; return r; }

constexpr double csqrt(double x){
  if(x <= 0.0) return 0.0;
  double g = x < 1.0 ? 1.0 : x;
  for(int i = 0; i < 64; ++i) g = 0.5*(g + x/g);
  return g;
}

constexpr double su2_cg(int j1,int m1,int j2,int m2,int j3,int m3){
  if(m1 + m2 != m3) return 0.0;
  int vmin = -j1 + j2 + m3;
  if(-j1 + m1 > vmin) vmin = -j1 + m1;
  if(0 > vmin) vmin = 0;
  int vmax = j2 + j3 + m1;
  if(j3 - j1 + j2 < vmax) vmax = j3 - j1 + j2;
  if(j3 + m3 < vmax) vmax = j3 + m3;
  double C = (double)(2*j3 + 1)
    * (fact(j3 + j1 - j2)*fact(j3 - j1 + j2)*fact(j1 + j2 - j3)*fact(j3 + m3)*fact(j3 - m3))
    / (fact(j1 + j2 + j3 + 1)*fact(j1 - m1)*fact(j1 + m1)*fact(j2 - m2)*fact(j2 + m2));
  double S = 0.0;
  for(int v = vmin; v <= vmax; ++v){
    double t = (fact(j2 + j3 + m1 - v)*fact(j1 - m1 + v))
      / (fact(v)*fact(j3 - j1 + j2 - v)*fact(j3 + m3 - v)*fact(v + j1 - j2 - m3));
    S += (((v + j2 + m2) & 1) ? -t : t);
  }
  return csqrt(C)*S;
}

struct C2 { double re; double im; };
constexpr C2 cmul(C2 a, C2 b){ return C2{a.re*b.re - a.im*b.im, a.re*b.im + a.im*b.re}; }

struct QM { C2 q[5][5]; };

constexpr QM rtc(int l){
  QM Q{};
  for(int a = 0; a < 5; ++a) for(int b = 0; b < 5; ++b) Q.q[a][b] = C2{0.0,0.0};
  const double inv = 1.0/csqrt(2.0);
  for(int m = -l; m < 0; ++m){
    Q.q[l+m][l-m] = C2{inv, 0.0};
    Q.q[l+m][l+m] = C2{0.0, -inv};
  }
  Q.q[l][l] = C2{1.0, 0.0};
  for(int m = 1; m <= l; ++m){
    const double sgn = (m & 1) ? -1.0 : 1.0;
    Q.q[l+m][l+m] = C2{sgn*inv, 0.0};
    Q.q[l+m][l-m] = C2{0.0, sgn*inv};
  }
  const C2 ph = (l == 0) ? C2{1.0,0.0} : (l == 1) ? C2{0.0,-1.0} : C2{-1.0,0.0}; // (-i)^l
  for(int a = 0; a < 2*l+1; ++a) for(int b = 0; b < 2*l+1; ++b) Q.q[a][b] = cmul(ph, Q.q[a][b]);
  return Q;
}

struct CG3 { double a[5][5][5]; };

constexpr CG3 so3(int l1,int l2,int l3){
  const QM Q1 = rtc(l1), Q2 = rtc(l2), Q3 = rtc(l3);
  const int d1 = 2*l1+1, d2 = 2*l2+1, d3 = 2*l3+1;
  CG3 R{};
  for(int a = 0; a < 5; ++a) for(int b = 0; b < 5; ++b) for(int c = 0; c < 5; ++c) R.a[a][b][c] = 0.0;
  for(int i = 0; i < d1; ++i) for(int k = 0; k < d2; ++k){
    const int m1 = i - l1, m2 = k - l2;
    if(m1 + m2 < -l3 || m1 + m2 > l3) continue;
    const int n = m1 + m2 + l3;
    const double c = su2_cg(l1, m1, l2, m2, l3, m1 + m2);
    if(c == 0.0) continue;
    for(int j = 0; j < d1; ++j){
      const C2 q1 = Q1.q[i][j]; if(q1.re == 0.0 && q1.im == 0.0) continue;
      for(int l = 0; l < d2; ++l){
        const C2 q2 = Q2.q[k][l]; if(q2.re == 0.0 && q2.im == 0.0) continue;
        const C2 q12 = cmul(q1, q2);
        for(int m = 0; m < d3; ++m){
          const C2 q3 = Q3.q[n][m]; if(q3.re == 0.0 && q3.im == 0.0) continue;
          const C2 p = cmul(q12, C2{q3.re, -q3.im});
          R.a[j][l][m] += c*p.re;
        }
      }
    }
  }
  return R;
}

constexpr int NCOMB = 15;
constexpr int CDEG[NCOMB] = {0,0,0, 1,1,1,1,1,1, 2,2,2,2,2,2};
constexpr int CNI [NCOMB] = {0,1,2, 0,1,1,1,2,2, 0,1,1,2,2,2};
constexpr int CNO [NCOMB] = {0,1,2, 1,0,1,2,1,2, 2,1,2,0,1,2};
constexpr int BOFF[NCOMB] = {0,1,4, 9,12,13,16,21,24, 29,34,37,42,43,46};
constexpr int BTOT = 51;

struct Tables { float cg[NCOMB][5][5][5]; };
constexpr Tables build(){
  Tables t{};
  for(int ci = 0; ci < NCOMB; ++ci){
    const CG3 r = so3(CDEG[ci], CNI[ci], CNO[ci]);
    for(int i = 0; i < 5; ++i) for(int j = 0; j < 5; ++j) for(int k = 0; k < 5; ++k)
      t.cg[ci][i][j][k] = (float)r.a[i][j][k];
  }
  return t;
}

} // namespace cgc

__device__ constexpr cgc::Tables TAB = cgc::build();

// ---------------------------------------------------------------------------
// fp16 pack/unpack helpers
// ---------------------------------------------------------------------------
DEVFN uint32_t pack2(float a, float b){
  __half2 h = __floats2half2_rn(a, b);
  return *reinterpret_cast<uint32_t*>(&h);
}
DEVFN float2 unpack2(uint32_t u){
  __half2 h = *reinterpret_cast<__half2*>(&u);
  return __half22float2(h);
}

// ---------------------------------------------------------------------------
// Per-node CG contraction from the moment matrix M[9][5] (this lane's x-half).
// ---------------------------------------------------------------------------

template<int CI, int H>
DEVFN void contract_combo(const float (&M)[9][5], float (&bp)[cgc::BTOT]){
  constexpr int DEG = cgc::CDEG[CI];
  constexpr int NI  = cgc::CNI[CI];
  constexpr int NO  = cgc::CNO[CI];
  constexpr int DI = 2*DEG + 1, DJ = 2*NI + 1, DK = 2*NO + 1;
  constexpr int SHO = (DEG == 0) ? 0 : ((DEG == 1) ? 1 : 4);
  constexpr int XB  = (NI  == 0) ? 0 : ((NI  == 1) ? 1 : 4);
  constexpr int BO  = cgc::BOFF[CI];

#pragma unroll
  for(int k = 0; k < DK; ++k){
    float acc = 0.0f; bool any = false;
#pragma unroll
    for(int i = 0; i < DI; ++i){
#pragma unroll
      for(int j = 0; j < DJ; ++j){
        const int xj = XB + j;                 // compile-time post-unroll
        if(H == 0 && xj >= 4) continue;
        if(H == 1 && xj <  4) continue;
        const float cg = TAB.cg[CI][i][j][k];
        if(cg != 0.0f){ acc += cg * M[SHO + i][H ? (xj - 4) : xj]; any = true; }
      }
    }
    if(any) bp[BO + k] += acc;
  }
}

template<int H>
DEVFN void all_contract(const float (&M)[9][5], float (&bp)[cgc::BTOT]){
  contract_combo< 0,H>(M, bp);
  contract_combo< 1,H>(M, bp);
  contract_combo< 2,H>(M, bp);
  contract_combo< 3,H>(M, bp);
  contract_combo< 4,H>(M, bp);
  contract_combo< 5,H>(M, bp);
  contract_combo< 6,H>(M, bp);
  contract_combo< 7,H>(M, bp);
  contract_combo< 8,H>(M, bp);
  contract_combo< 9,H>(M, bp);
  contract_combo<10,H>(M, bp);
  contract_combo<11,H>(M, bp);
  contract_combo<12,H>(M, bp);
  contract_combo<13,H>(M, bp);
  contract_combo<14,H>(M, bp);
}

template<int CI>
DEVFN void combo_mix(const float (&B)[cgc::BTOT], float (&msg)[72],
                     const float* __restrict__ W, int c){
  constexpr int NO = cgc::CNO[CI];
  constexpr int DK = 2*NO + 1;
  constexpr int OO = (NO == 0) ? 0 : ((NO == 1) ? 8 : 32);
  constexpr int BO = cgc::BOFF[CI];
  const float* __restrict__ Wc = W + CI*64 + c*8;
#pragma unroll
  for(int o = 0; o < 8; ++o){
    const float w = Wc[o];
#pragma unroll
    for(int k = 0; k < DK; ++k) msg[OO + o*DK + k] += B[BO + k]*w;
  }
}

DEVFN void all_combo_mix(const float (&B)[cgc::BTOT], float (&msg)[72],
                         const float* __restrict__ W, int c){
  combo_mix< 0>(B, msg, W, c);
  combo_mix< 1>(B, msg, W, c);
  combo_mix< 2>(B, msg, W, c);
  combo_mix< 3>(B, msg, W, c);
  combo_mix< 4>(B, msg, W, c);
  combo_mix< 5>(B, msg, W, c);
  combo_mix< 6>(B, msg, W, c);
  combo_mix< 7>(B, msg, W, c);
  combo_mix< 8>(B, msg, W, c);
  combo_mix< 9>(B, msg, W, c);
  combo_mix<10>(B, msg, W, c);
  combo_mix<11>(B, msg, W, c);
  combo_mix<12>(B, msg, W, c);
  combo_mix<13>(B, msg, W, c);
  combo_mix<14>(B, msg, W, c);
}

// Shared node epilogue. OUTM: 0 = fp32 [N][72] rows; 1 = fp16 [N][8][12] slabs.
template<int OUTM>
DEVFN void node_epilogue(const float (&M)[9][5], const float* __restrict__ W,
                         int c, int sub, int g, void* __restrict__ outv){
  float bp[cgc::BTOT];
#pragma unroll
  for(int i = 0; i < cgc::BTOT; ++i) bp[i] = 0.0f;
  if(sub == 0) all_contract<0>(M, bp);
  else         all_contract<1>(M, bp);

#pragma unroll
  for(int i = 0; i < cgc::BTOT; ++i) bp[i] += __shfl_xor(bp[i], 8);

  float msg[72];
#pragma unroll
  for(int d = 0; d < 72; ++d) msg[d] = 0.0f;
  all_combo_mix(bp, msg, W, c);

#pragma unroll
  for(int d = 0; d < 72; ++d){
    msg[d] += __shfl_xor(msg[d], 1);
    msg[d] += __shfl_xor(msg[d], 2);
    msg[d] += __shfl_xor(msg[d], 4);
  }

  if constexpr(OUTM == 1){
    // fp16 packed slab write: lane c (sub==0) writes its channel's 12-half slab.
    if(sub == 0){
      float m0,m1,m2,m3,m4,m5,m6,m7,m8;
      switch(c){
        case 0: m0=msg[0]; m1=msg[ 8]; m2=msg[ 9]; m3=msg[10];
                m4=msg[32]; m5=msg[33]; m6=msg[34]; m7=msg[35]; m8=msg[36]; break;
        case 1: m0=msg[1]; m1=msg[11]; m2=msg[12]; m3=msg[13];
                m4=msg[37]; m5=msg[38]; m6=msg[39]; m7=msg[40]; m8=msg[41]; break;
        case 2: m0=msg[2]; m1=msg[14]; m2=msg[15]; m3=msg[16];
                m4=msg[42]; m5=msg[43]; m6=msg[44]; m7=msg[45]; m8=msg[46]; break;
        case 3: m0=msg[3]; m1=msg[17]; m2=msg[18]; m3=msg[19];
                m4=msg[47]; m5=msg[48]; m6=msg[49]; m7=msg[50]; m8=msg[51]; break;
        case 4: m0=msg[4]; m1=msg[20]; m2=msg[21]; m3=msg[22];
                m4=msg[52]; m5=msg[53]; m6=msg[54]; m7=msg[55]; m8=msg[56]; break;
        case 5: m0=msg[5]; m1=msg[23]; m2=msg[24]; m3=msg[25];
                m4=msg[57]; m5=msg[58]; m6=msg[59]; m7=msg[60]; m8=msg[61]; break;
        case 6: m0=msg[6]; m1=msg[26]; m2=msg[27]; m3=msg[28];
                m4=msg[62]; m5=msg[63]; m6=msg[64]; m7=msg[65]; m8=msg[66]; break;
        default:m0=msg[7]; m1=msg[29]; m2=msg[30]; m3=msg[31];
                m4=msg[67]; m5=msg[68]; m6=msg[69]; m7=msg[70]; m8=msg[71]; break;
      }
      uint2 u01, u23, u45;
      u01.x = pack2(m0, m1); u01.y = pack2(m2, m3);
      u23.x = pack2(m4, m5); u23.y = pack2(m6, m7);
      u45.x = pack2(m8, 0.f); u45.y = 0u;
      uint2* op = (uint2*)((uint32_t*)outv + (size_t)g*48 + c*6);
      op[0] = u01; op[1] = u23; op[2] = u45;
    }
  } else {
    if(sub == 0 && c == 0){
      float4* op = (float4*)((float*)outv + (size_t)g*72);
#pragma unroll
      for(int u = 0; u < 18; ++u){
        float4 v;
        v.x = msg[4*u + 0]; v.y = msg[4*u + 1];
        v.z = msg[4*u + 2]; v.w = msg[4*u + 3];
        op[u] = v;
      }
    }
  }
}

// ---------------------------------------------------------------------------
// CSR build — verbatim from round 3 (passed thirteen times).
// ---------------------------------------------------------------------------

__global__ __launch_bounds__(256)
void hist_kernel(const int* __restrict__ ei, int* __restrict__ cnt, int E){
  const int e = blockIdx.x*256 + threadIdx.x;
  if(e < E) atomicAdd(&cnt[ei[E + e]], 1);
}

__global__ __launch_bounds__(256)
void chunk_scan_kernel(const int* __restrict__ cnt, int* __restrict__ off,
                       int* __restrict__ chunkSum, int N){
  __shared__ int buf[1024];
  const int tid = threadIdx.x;
  const int base = blockIdx.x*1024;
  for(int j = tid; j < 1024; j += 256) buf[j] = (base + j < N) ? cnt[base + j] : 0;
  __syncthreads();
  if(tid == 0){
    int run = 0;
    for(int j = 0; j < 1024; ++j){ const int v = buf[j]; buf[j] = run; run += v; }
    chunkSum[blockIdx.x] = run;
  }
  __syncthreads();
  for(int j = tid; j < 1024; j += 256) if(base + j < N) off[base + j] = buf[j];
}

__global__ __launch_bounds__(64)
void chunk_offsets_kernel(int* __restrict__ chunkSum, int* __restrict__ offN, int C){
  if(threadIdx.x == 0 && blockIdx.x == 0){
    int run = 0;
    for(int c = 0; c < C; ++c){ const int v = chunkSum[c]; chunkSum[c] = run; run += v; }
    offN[0] = run;
  }
}

__global__ __launch_bounds__(256)
void apply_offsets_kernel(int* __restrict__ off, int* __restrict__ cursor,
                          const int* __restrict__ chunkSum, int N){
  const int i = blockIdx.x*256 + threadIdx.x;
  if(i < N){
    const int o = off[i] + chunkSum[i >> 10];
    off[i] = o;
    cursor[i] = o;
  }
}

// tier-0 fill: srcs[p] and bucket-order-permuted fp16 sh row (12 halfs).
__global__ __launch_bounds__(256)
void fill_permute_h(const int* __restrict__ ei, int* __restrict__ cursor,
                    int* __restrict__ srcs, uint32_t* __restrict__ shpp,
                    const float* __restrict__ sh0, const float* __restrict__ sh1,
                    const float* __restrict__ sh2, int E){
  const int e = blockIdx.x*256 + threadIdx.x;
  if(e >= E) return;
  const int t = ei[E + e];
  const int p = atomicAdd(&cursor[t], 1);
  srcs[p] = ei[e];
  uint2 u01, u23, u45;
  u01.x = pack2(sh0[e],     sh1[3*e]);
  u01.y = pack2(sh1[3*e+1], sh1[3*e+2]);
  u23.x = pack2(sh2[5*e],   sh2[5*e+1]);
  u23.y = pack2(sh2[5*e+2], sh2[5*e+3]);
  u45.x = pack2(sh2[5*e+4], 0.f);
  u45.y = 0u;
  uint2* op = (uint2*)(shpp + (size_t)p*6);
  op[0] = u01; op[1] = u23; op[2] = u45;
}

// tier-2 fill (bare fallback, proven round 3)
__global__ __launch_bounds__(256)
void fill_kernel(const int* __restrict__ ei, int* __restrict__ cursor,
                 int* __restrict__ bucket, int E){
  const int e = blockIdx.x*256 + threadIdx.x;
  if(e >= E) return;
  const int t = ei[E + e];
  const int p = atomicAdd(&cursor[t], 1);
  bucket[p] = e;
}

// ---------------------------------------------------------------------------
// x packing to fp16 slabs: [n][72] f32 -> xph [n][8][12] halfs
// ---------------------------------------------------------------------------
__global__ __launch_bounds__(256)
void pack_x_h(const float* __restrict__ xin, uint32_t* __restrict__ xph, int N){
  const int idx = blockIdx.x*256 + threadIdx.x;
  if(idx >= N*8) return;
  const int n = idx >> 3, c = idx & 7;
  const float* row = xin + (size_t)n*72;
  uint2 u01, u23, u45;
  u01.x = pack2(row[c],        row[8+3*c]);
  u01.y = pack2(row[9+3*c],    row[10+3*c]);
  u23.x = pack2(row[32+5*c],   row[33+5*c]);
  u23.y = pack2(row[34+5*c],   row[35+5*c]);
  u45.x = pack2(row[36+5*c],   0.f);
  u45.y = 0u;
  uint2* op = (uint2*)(xph + (size_t)n*48 + c*6);
  op[0] = u01; op[1] = u23; op[2] = u45;
}

// ---------------------------------------------------------------------------
// Tier-0 gather (fp16 permuted streams): 16 lanes/node = 8 channels x 2 x-halves.
// Per edge p: srcs[p] (stream), shpp[p] (stream 24B), xph[src] (random 96B row).
// 3-deep pipeline; fp32 moment accumulate; shared epilogue. No atomics/LDS.
// (R13-proven form: best measured total, 314.5 us.)
// ---------------------------------------------------------------------------

DEVFN void load_edge_h(float (&sh)[9], float (&xs)[5],
                       int p, int c, int sub,
                       const int* __restrict__ srcs,
                       const uint32_t* __restrict__ shpp,
                       const uint32_t* __restrict__ xph){
  const uint2* sp = (const uint2*)(shpp + (size_t)p*6);
  const uint2 a = sp[0], b = sp[1];
  const uint32_t w4 = shpp[(size_t)p*6 + 4];
  float2 f;
  f = unpack2(a.x); sh[0]=f.x; sh[1]=f.y;
  f = unpack2(a.y); sh[2]=f.x; sh[3]=f.y;
  f = unpack2(b.x); sh[4]=f.x; sh[5]=f.y;
  f = unpack2(b.y); sh[6]=f.x; sh[7]=f.y;
  f = unpack2(w4);  sh[8]=f.x;

  const int src = srcs[p];
  const uint32_t* base = xph + (size_t)src*48 + c*6;
  const uint2 xv = *(const uint2*)(base + sub*2);    // words 0-1 or 2-3
  const uint32_t x8w = base[4];
  f = unpack2(xv.x); xs[0]=f.x; xs[1]=f.y;
  f = unpack2(xv.y); xs[2]=f.x; xs[3]=f.y;
  f = unpack2(x8w);
  xs[4] = sub ? f.x : 0.0f;
}

DEVFN void outer_acc(const float (&sh)[9], const float (&xs)[5], float (&M)[9][5]){
#pragma unroll
  for(int i = 0; i < 9; ++i)
#pragma unroll
    for(int j = 0; j < 5; ++j)
      M[i][j] += sh[i]*xs[j];
}

template<int OUTM>
__global__ __launch_bounds__(256)
void gather_h(const uint32_t* __restrict__ xph,
              const uint32_t* __restrict__ shpp,
              const int*   __restrict__ srcs,
              const int*   __restrict__ off,
              const float* __restrict__ W,
              void* __restrict__ out,
              int N){
  const int t   = blockIdx.x*256 + threadIdx.x;
  const int g   = t >> 4;
  const int c   = t & 7;
  const int sub = (t >> 3) & 1;
  if(g >= N) return;

  const int pStart = off[g];
  const int pEnd   = off[g + 1];

  float M[9][5];
#pragma unroll
  for(int a = 0; a < 9; ++a)
#pragma unroll
    for(int b = 0; b < 5; ++b) M[a][b] = 0.0f;

  if(pStart < pEnd){
    float shA[9], xsA[5], shB[9], xsB[5], shC[9], xsC[5];
    int p = pStart;
    load_edge_h(shA, xsA, p, c, sub, srcs, shpp, xph);
    { const int pn = (p + 1 < pEnd) ? p + 1 : p;
      load_edge_h(shB, xsB, pn, c, sub, srcs, shpp, xph); }
    while(true){
      { const int pn = (p + 2 < pEnd) ? p + 2 : p;
        load_edge_h(shC, xsC, pn, c, sub, srcs, shpp, xph); }
      outer_acc(shA, xsA, M);
      ++p; if(p >= pEnd) break;
      { const int pn = (p + 2 < pEnd) ? p + 2 : p;
        load_edge_h(shA, xsA, pn, c, sub, srcs, shpp, xph); }
      outer_acc(shB, xsB, M);
      ++p; if(p >= pEnd) break;
      { const int pn = (p + 2 < pEnd) ? p + 2 : p;
        load_edge_h(shB, xsB, pn, c, sub, srcs, shpp, xph); }
      outer_acc(shC, xsC, M);
      ++p; if(p >= pEnd) break;
    }
  }

  node_epilogue<OUTM>(M, W, c, sub, g, out);
}

// ---------------------------------------------------------------------------
// Tier-2 fallback gather (bare fp32, proven structure).
// ---------------------------------------------------------------------------

DEVFN void load_edge_f(float (&sh)[9], float (&xs)[5],
                       int eid, int src, int c, int sub,
                       const float* __restrict__ x,
                       const float* __restrict__ sh0, const float* __restrict__ sh1,
                       const float* __restrict__ sh2){
  sh[0] = sh0[eid];
  sh[1] = sh1[3*eid+0]; sh[2] = sh1[3*eid+1]; sh[3] = sh1[3*eid+2];
  sh[4] = sh2[5*eid+0]; sh[5] = sh2[5*eid+1]; sh[6] = sh2[5*eid+2];
  sh[7] = sh2[5*eid+3]; sh[8] = sh2[5*eid+4];
  const float* xrow = x + (size_t)src*72;
  if(sub == 0){
    xs[0] = xrow[c];
    xs[1] = xrow[8+3*c]; xs[2] = xrow[9+3*c]; xs[3] = xrow[10+3*c];
    xs[4] = 0.0f;
  } else {
#pragma unroll
    for(int k = 0; k < 5; ++k) xs[k] = xrow[32 + 5*c + k];
  }
}

__global__ __launch_bounds__(256)
void gather_f(const float* __restrict__ x,
              const int*   __restrict__ ei,
              const float* __restrict__ sh0,
              const float* __restrict__ sh1,
              const float* __restrict__ sh2,
              const int*   __restrict__ off,
              const int*   __restrict__ bucket,
              const float* __restrict__ W,
              float* __restrict__ out,
              int N){
  const int t   = blockIdx.x*256 + threadIdx.x;
  const int g   = t >> 4;
  const int c   = t & 7;
  const int sub = (t >> 3) & 1;
  if(g >= N) return;

  const int pStart = off[g];
  const int pEnd   = off[g + 1];

  float M[9][5];
#pragma unroll
  for(int a = 0; a < 9; ++a)
#pragma unroll
    for(int b = 0; b < 5; ++b) M[a][b] = 0.0f;

  if(pStart < pEnd){
    float shA[9], xsA[5], shB[9], xsB[5], shC[9], xsC[5];
    int p = pStart;
    { const int eid = bucket[p]; const int src = ei[eid];
      load_edge_f(shA, xsA, eid, src, c, sub, x, sh0, sh1, sh2); }
    { const int pn = (p + 1 < pEnd) ? p + 1 : p;
      const int eid = bucket[pn]; const int src = ei[eid];
      load_edge_f(shB, xsB, eid, src, c, sub, x, sh0, sh1, sh2); }
    while(true){
      { const int pn = (p + 2 < pEnd) ? p + 2 : p;
        const int eid = bucket[pn]; const int src = ei[eid];
        load_edge_f(shC, xsC, eid, src, c, sub, x, sh0, sh1, sh2); }
      outer_acc(shA, xsA, M);
      ++p; if(p >= pEnd) break;
      { const int pn = (p + 2 < pEnd) ? p + 2 : p;
        const int eid = bucket[pn]; const int src = ei[eid];
        load_edge_f(shA, xsA, eid, src, c, sub, x, sh0, sh1, sh2); }
      outer_acc(shB, xsB, M);
      ++p; if(p >= pEnd) break;
      { const int pn = (p + 2 < pEnd) ? p + 2 : p;
        const int eid = bucket[pn]; const int src = ei[eid];
        load_edge_f(shB, xsB, eid, src, c, sub, x, sh0, sh1, sh2); }
      outer_acc(shC, xsC, M);
      ++p; if(p >= pEnd) break;
    }
  }

  node_epilogue<0>(M, W, c, sub, g, (void*)out);
}

// ---------------------------------------------------------------------------

extern "C" void kernel_launch(void* const* d_in, const int* in_sizes, int n_in,
                              void* d_out, int out_size, void* d_ws, size_t ws_size,
                              hipStream_t stream){
  const float* node = (const float*)d_in[0];
  const int*   ei   = (const int*)  d_in[1];
  const float* sh0  = (const float*)d_in[2];
  const float* sh1  = (const float*)d_in[3];
  const float* sh2  = (const float*)d_in[4];
  const float* wts  = (const float*)d_in[5];
  float* out = (float*)d_out;

  const int E = in_sizes[1]/2;
  const int N = in_sizes[0]/72;
  const int C = (N + 1023)/1024;

  // ---- workspace tiers (4-byte units) ----
  size_t baseI = (size_t)3*N + 65;
  baseI = (baseI + 3) & ~(size_t)3;
  const size_t availI = ws_size/4;
  // tier 0: srcs[E] + shpp[6E words] + xph1[48N] + xph2[48N]
  const size_t t0Need = baseI + (size_t)E + (size_t)6*E + (size_t)48*N + (size_t)48*N;
  const int tier = (availI >= t0Need) ? 0 : 2;

  int* ws_i = (int*)d_ws;
  int* cnt      = ws_i;                       // [N]
  int* off      = ws_i + N;                   // [N+1]
  int* cursor   = ws_i + 2*N + 1;             // [N]
  int* chunkSum = ws_i + 3*N + 1;             // [C] (<=64)
  size_t cur = baseI;

  int*      srcs = nullptr;
  uint32_t* shpp = nullptr;
  uint32_t* xph1 = nullptr;
  uint32_t* xph2 = nullptr;
  int*      bucket = nullptr;
  float*    inter  = nullptr;

  if(tier == 0){
    srcs = (int*)(ws_i + cur);      cur += (size_t)E;
    shpp = (uint32_t*)(ws_i + cur); cur += (size_t)6*E;
    xph1 = (uint32_t*)(ws_i + cur); cur += (size_t)48*N;
    xph2 = (uint32_t*)(ws_i + cur); cur += (size_t)48*N;
  } else {
    bucket = (int*)(ws_i + cur);   cur += (size_t)E;
    inter  = (float*)(ws_i + cur); cur += (size_t)72*N;
  }

  const int eBlocks = (E + 255)/256;
  const int nBlocks = (N + 255)/256;
  const int gBlocks = ((size_t)16*N + 255)/256;   // 16 lanes per node

  // CSR build (targets identical for both layers)
  hipMemsetAsync(cnt, 0, (size_t)N*sizeof(int), stream);
  hist_kernel<<<eBlocks, 256, 0, stream>>>(ei, cnt, E);
  chunk_scan_kernel<<<C, 256, 0, stream>>>(cnt, off, chunkSum, N);
  chunk_offsets_kernel<<<1, 64, 0, stream>>>(chunkSum, off + N, C);
  apply_offsets_kernel<<<nBlocks, 256, 0, stream>>>(off, cursor, chunkSum, N);

  const float* w2 = wts + cgc::NCOMB*64;

  if(tier == 0){
    fill_permute_h<<<eBlocks, 256, 0, stream>>>(ei, cursor, srcs, shpp,
                                                sh0, sh1, sh2, E);
    pack_x_h<<<((size_t)8*N + 255)/256, 256, 0, stream>>>(node, xph1, N);
    // layer 1: xph1 -> xph2 (fp16 slabs)
    gather_h<1><<<gBlocks, 256, 0, stream>>>(xph1, shpp, srcs, off, wts, (void*)xph2, N);
    // layer 2: xph2 -> out (fp32)
    gather_h<0><<<gBlocks, 256, 0, stream>>>(xph2, shpp, srcs, off, w2, (void*)out, N);
  } else {
    fill_kernel<<<eBlocks, 256, 0, stream>>>(ei, cursor, bucket, E);
    gather_f<<<gBlocks, 256, 0, stream>>>(node,  ei, sh0, sh1, sh2,
                                          off, bucket, wts, inter, N);
    gather_f<<<gBlocks, 256, 0, stream>>>(inter, ei, sh0, sh1, sh2,
                                          off, bucket, w2, out, N);
  }
}